// Round 4
// baseline (179.039 us; speedup 1.0000x reference)
//
#include <hip/hip_runtime.h>

typedef unsigned short u16;
typedef unsigned int   u32;
typedef short  short8  __attribute__((ext_vector_type(8)));
typedef __bf16 bf16x8  __attribute__((ext_vector_type(8)));
typedef float  f32x4   __attribute__((ext_vector_type(4)));

#define POWER_ITERS 8

// ---------- helpers ----------
__device__ __forceinline__ u16 f2bf(float f){
  return __builtin_bit_cast(u16, (__bf16)f);           // RNE, hw cvt on gfx950
}
__device__ __forceinline__ u32 pack2bf(float a, float b){
  return (u32)__builtin_bit_cast(u16, (__bf16)a) |
        ((u32)__builtin_bit_cast(u16, (__bf16)b) << 16);
}
__device__ __forceinline__ float bf2f(u16 h){ return __uint_as_float(((u32)h) << 16); }

__device__ __forceinline__ f32x4 mfma_bf16(short8 a, short8 b, f32x4 c){
  return __builtin_amdgcn_mfma_f32_16x16x32_bf16(
      __builtin_bit_cast(bf16x8, a), __builtin_bit_cast(bf16x8, b), c, 0, 0, 0);
}

// swizzled LDS address (u16 units) of element [row][k] of a 64x64 matrix.
__device__ __forceinline__ int swz(int row, int k){
  return row*64 + ((((k >> 3) ^ (row & 7)) << 3) | (k & 7));
}
__device__ __forceinline__ short8 lds_frag(const u16* P, int row, int k0){
  int pos = (k0 >> 3) ^ (row & 7);
  return *(const short8*)(P + row*64 + pos*8);
}
__device__ __forceinline__ short8 g_frag(const u16* __restrict__ M, int row, int k0){
  return *(const short8*)(M + row*64 + k0);
}

// write C/D regs (matrix X, C-layout) as X^T into swizzled LDS (bf16), scaled.
__device__ __forceinline__ void write_CT_lds_s(u16* Pt, int lane, const f32x4 (&C)[4][4], float s){
  const int m16 = lane & 15, q = lane >> 4;
#pragma unroll
  for(int i = 0; i < 4; i++){
    const int r0 = i*16 + q*4;
#pragma unroll
    for(int j = 0; j < 4; j++){
      const int c = j*16 + m16;
      const int addr = c*64 + ((((r0 >> 3) ^ (c & 7)) << 3) | (r0 & 7));
      u32 lo = pack2bf(C[i][j][0]*s, C[i][j][1]*s);
      u32 hi = pack2bf(C[i][j][2]*s, C[i][j][3]*s);
      *(uint2*)(Pt + addr) = make_uint2(lo, hi);
    }
  }
}
__device__ __forceinline__ void write_CT_lds(u16* Pt, int lane, const f32x4 (&C)[4][4]){
  write_CT_lds_s(Pt, lane, C, 1.f);
}

// A from LDS zone (row-major swizzled) times P (Pt holds P^T); writes P'^T back.
__device__ __forceinline__ void chain_step_L(const u16* Az, u16* Pt, int lane, f32x4 (&C)[4][4]){
  const int m16 = lane & 15, q = lane >> 4;
  short8 Af[2][4], Bf[2][4];
#pragma unroll
  for(int ks = 0; ks < 2; ks++){
    const int k0 = ks*32 + q*8;
#pragma unroll
    for(int t = 0; t < 4; t++){
      Af[ks][t] = lds_frag(Az, t*16 + m16, k0);
      Bf[ks][t] = lds_frag(Pt, t*16 + m16, k0);
    }
  }
#pragma unroll
  for(int i = 0; i < 4; i++)
#pragma unroll
    for(int j = 0; j < 4; j++)
      C[i][j] = f32x4{0.f, 0.f, 0.f, 0.f};
#pragma unroll
  for(int ks = 0; ks < 2; ks++)
#pragma unroll
    for(int i = 0; i < 4; i++)
#pragma unroll
      for(int j = 0; j < 4; j++)
        C[i][j] = mfma_bf16(Af[ks][i], Bf[ks][j], C[i][j]);
  write_CT_lds(Pt, lane, C);
}

// init: P = N (global row-major) -> store P^T into swizzled LDS
__device__ __forceinline__ void load_Pt_transpose(const u16* __restrict__ N, u16* Pt, int lane){
#pragma unroll
  for(int g = 0; g < 8; g++){
    short8 v = *(const short8*)(N + lane*64 + g*8);
#pragma unroll
    for(int t = 0; t < 8; t++){
      int k = g*8 + t;
      Pt[swz(k, lane)] = (u16)v[t];
    }
  }
}

__device__ __forceinline__ float wave_max(float mx){
  for(int off = 32; off; off >>= 1) mx = fmaxf(mx, __shfl_xor(mx, off, 64));
  return mx;
}

// ---------- rolled chain loop with A-prefetch; leaves final product in C ----------
__device__ __forceinline__ void chain_loop(const u16* __restrict__ mats, const int* __restrict__ seq,
                                           int node, int chain_len, u16* Pt, int lane,
                                           f32x4 (&C)[4][4]){
  const int m16 = lane & 15, q = lane >> 4;
  int sv = 0;
  if(seq && lane < chain_len) sv = seq[node*chain_len + lane];
  int idx0 = seq ? __shfl(sv, 0, 64) : node*chain_len;
  load_Pt_transpose(mats + (size_t)idx0*4096, Pt, lane);
  int idx1 = seq ? __shfl(sv, 1, 64) : node*chain_len + 1;
  short8 Af[2][4];
  {
    const u16* Ag = mats + (size_t)idx1*4096;
#pragma unroll
    for(int ks = 0; ks < 2; ks++)
#pragma unroll
      for(int t = 0; t < 4; t++) Af[ks][t] = g_frag(Ag, t*16 + m16, ks*32 + q*8);
  }
#pragma unroll 1
  for(int j = 1; j < chain_len; j++){
    short8 Bf[2][4];
#pragma unroll
    for(int ks = 0; ks < 2; ks++)
#pragma unroll
      for(int t = 0; t < 4; t++) Bf[ks][t] = lds_frag(Pt, t*16 + m16, ks*32 + q*8);
    short8 An[2][4];
    if(j + 1 < chain_len){
      int idx = seq ? __shfl(sv, j + 1, 64) : node*chain_len + j + 1;
      const u16* Ag = mats + (size_t)idx*4096;
#pragma unroll
      for(int ks = 0; ks < 2; ks++)
#pragma unroll
        for(int t = 0; t < 4; t++) An[ks][t] = g_frag(Ag, t*16 + m16, ks*32 + q*8);
    } else {
#pragma unroll
      for(int ks = 0; ks < 2; ks++)
#pragma unroll
        for(int t = 0; t < 4; t++) An[ks][t] = Af[ks][t];
    }
#pragma unroll
    for(int i = 0; i < 4; i++)
#pragma unroll
      for(int jj = 0; jj < 4; jj++) C[i][jj] = f32x4{0.f,0.f,0.f,0.f};
#pragma unroll
    for(int ks = 0; ks < 2; ks++)
#pragma unroll
      for(int i = 0; i < 4; i++)
#pragma unroll
        for(int jj = 0; jj < 4; jj++)
          C[i][jj] = mfma_bf16(Af[ks][i], Bf[ks][jj], C[i][jj]);
    if(j < chain_len - 1) write_CT_lds(Pt, lane, C);   // last result stays in C only
#pragma unroll
    for(int ks = 0; ks < 2; ks++)
#pragma unroll
      for(int t = 0; t < 4; t++) Af[ks][t] = An[ks][t];
  }
}

// chain -> normalized node (bf16, row-major GLOBAL) + log2-scale into S_acc
__device__ void run_chain(const u16* __restrict__ mats, const int* __restrict__ seq,
                          int node, int chain_len, u16* Pt, u16* __restrict__ outp,
                          int* __restrict__ S_acc, int lane){
  f32x4 C[4][4];
  chain_loop(mats, seq, node, chain_len, Pt, lane, C);
  float mx = 0.f;
#pragma unroll
  for(int i = 0; i < 4; i++)
#pragma unroll
    for(int j = 0; j < 4; j++)
#pragma unroll
      for(int t = 0; t < 4; t++) mx = fmaxf(mx, C[i][j][t]);   // entries all positive
  mx = wave_max(mx);
  int e; (void)frexpf(mx, &e);
  float s = ldexpf(1.f, -e);
  const int m16 = lane & 15, q = lane >> 4;
#pragma unroll
  for(int i = 0; i < 4; i++)
#pragma unroll
    for(int j = 0; j < 4; j++)
#pragma unroll
      for(int t = 0; t < 4; t++)
        outp[(i*16 + q*4 + t)*64 + j*16 + m16] = f2bf(C[i][j][t] * s);
  if(lane == 0) atomicAdd(S_acc, e);
}

// ---------- power iteration: 8 waves, one Kraus op per wave ----------
__device__ __forceinline__ void pw_stages(const short8 (&Kf)[2][4], const u16* rho, u16* zw,
                                          int m16, int q, int lane){
  short8 Ar[2][4];
#pragma unroll
  for(int ks = 0; ks < 2; ks++)
#pragma unroll
    for(int t = 0; t < 4; t++)
      Ar[ks][t] = lds_frag(rho, t*16 + m16, ks*32 + q*8);
  f32x4 C[4][4];
#pragma unroll
  for(int i = 0; i < 4; i++)
#pragma unroll
    for(int j = 0; j < 4; j++) C[i][j] = f32x4{0.f,0.f,0.f,0.f};
#pragma unroll
  for(int ks = 0; ks < 2; ks++)
#pragma unroll
    for(int i = 0; i < 4; i++)
#pragma unroll
      for(int j = 0; j < 4; j++)
        C[i][j] = mfma_bf16(Ar[ks][i], Kf[ks][j], C[i][j]);
  write_CT_lds(zw, lane, C);            // zw = Kw*rho (rho symmetric)
  short8 Bt[2][4];
#pragma unroll
  for(int ks = 0; ks < 2; ks++)
#pragma unroll
    for(int t = 0; t < 4; t++)
      Bt[ks][t] = lds_frag(zw, t*16 + m16, ks*32 + q*8);
#pragma unroll
  for(int i = 0; i < 4; i++)
#pragma unroll
    for(int j = 0; j < 4; j++) C[i][j] = f32x4{0.f,0.f,0.f,0.f};
#pragma unroll
  for(int ks = 0; ks < 2; ks++)
#pragma unroll
    for(int i = 0; i < 4; i++)
#pragma unroll
      for(int j = 0; j < 4; j++)
        C[i][j] = mfma_bf16(Kf[ks][i], Bt[ks][j], C[i][j]);
  write_CT_lds(zw, lane, C);            // zone_w = Kw*rho*Kw^T
}

__device__ void power_iter(const u16* __restrict__ Kdir, float* __restrict__ rho_out,
                           char* smem, int iters){
  u16*   zones = (u16*)smem;
  u16*   rho   = (u16*)(smem + 65536);
  float* red   = (float*)(smem + 73728);
  const int tid = threadIdx.x, lane = tid & 63, wave = tid >> 6;
  u16* zw = zones + wave*4096;
  const int m16 = lane & 15, q = lane >> 4;
  const float S13 = 1.f/8192.f;          // fixed per-iter scale (lambda ~ 2^13)

  short8 Kf[2][4];
  {
    const u16* Kw = Kdir + (size_t)wave*4096;
#pragma unroll
    for(int ks = 0; ks < 2; ks++)
#pragma unroll
      for(int t = 0; t < 4; t++)
        Kf[ks][t] = g_frag(Kw, t*16 + m16, ks*32 + q*8);
  }

  const int row = tid >> 3, k0 = (tid & 7) * 8;
  const int rpos = row*64 + (((tid & 7) ^ (row & 7)) << 3);
  {
    short8 b;
#pragma unroll
    for(int j = 0; j < 8; j++) b[j] = (row == k0 + j) ? (short)f2bf(1.f/64.f) : (short)0;
    *(short8*)(rho + rpos) = b;
  }
  __syncthreads();

#pragma unroll 1
  for(int it = 0; it < iters; it++){
    pw_stages(Kf, rho, zw, m16, q, lane);
    __syncthreads();

    float v[8];
#pragma unroll
    for(int j = 0; j < 8; j++) v[j] = 0.f;
#pragma unroll
    for(int z = 0; z < 8; z++){
      short8 f = lds_frag(zones + z*4096, row, k0);
#pragma unroll
      for(int j = 0; j < 8; j++) v[j] += bf2f((u16)f[j]);
    }
    if(it != iters - 1){
      u32 w0 = pack2bf(v[0]*S13, v[1]*S13), w1 = pack2bf(v[2]*S13, v[3]*S13);
      u32 w2 = pack2bf(v[4]*S13, v[5]*S13), w3 = pack2bf(v[6]*S13, v[7]*S13);
      *(uint4*)(rho + rpos) = make_uint4(w0, w1, w2, w3);
      __syncthreads();
    } else {
      float pd = (k0 <= row && row < k0 + 8) ? v[row - k0] : 0.f;
      for(int off = 32; off; off >>= 1) pd += __shfl_xor(pd, off, 64);
      if(lane == 0) red[wave] = pd;
      __syncthreads();
      float tr = 0.f;
#pragma unroll
      for(int w = 0; w < 8; w++) tr += red[w];
      float inv = 1.f / tr;
#pragma unroll
      for(int j = 0; j < 8; j++) rho_out[row*64 + k0 + j] = v[j] * inv;
    }
  }
}

// ---------- kernels ----------
__global__ void k_setup(const float* __restrict__ K, u16* __restrict__ Kbf,
                        u16* __restrict__ KTbf, int* S_acc, float* mu_acc){
  int tid = blockIdx.x*256 + threadIdx.x;
  if(tid < 32768){
    float f = K[tid];
    u16 h = f2bf(f);
    Kbf[tid] = h;
    int a = tid >> 12, r = (tid >> 6) & 63, c = tid & 63;
    KTbf[(a << 12) + (c << 6) + r] = h;
  }
  if(tid == 0){ *S_acc = 0; *mu_acc = 0.f; }
}

// blocks 0,1: power iteration. blocks 2..129: level-1 chains (1024 nodes of 16).
__global__ __launch_bounds__(512, 2) void k_main(const u16* __restrict__ Kbf, const u16* __restrict__ KTbf,
                                                 const int* __restrict__ seq,
                                                 float* __restrict__ rho_r, float* __restrict__ rho_l,
                                                 u16* __restrict__ N1, int* __restrict__ S_acc){
  __shared__ __align__(16) char smem[73792];
  int b = blockIdx.x;
  if(b < 2){
    power_iter(b == 0 ? Kbf : KTbf, b == 0 ? rho_r : rho_l, smem, POWER_ITERS);
  } else {
    int lane = threadIdx.x & 63, wave = threadIdx.x >> 6;
    int node = (b - 2)*8 + wave;
    u16* Pt = (u16*)smem + wave*4096;
    run_chain(Kbf, seq, node, 16, Pt, N1 + (size_t)node*4096, S_acc, lane);
  }
}

// blocks 0..7: level-2 chains (64 nodes of 16 over N1). blocks 8..23: fp32 Rayleigh lambda.
__global__ __launch_bounds__(512) void k_mid(const u16* __restrict__ N1, u16* __restrict__ N2,
                                             int* __restrict__ S_acc,
                                             const float* __restrict__ K,
                                             const float* __restrict__ rho_l,
                                             float* __restrict__ mu_acc){
  __shared__ __align__(16) u16 Pt8[8][4096];
  int lane = threadIdx.x & 63, wave = threadIdx.x >> 6;
  int b = blockIdx.x;
  if(b < 8){
    int node = b*8 + wave;
    run_chain(N1, nullptr, node, 16, Pt8[wave], N2 + (size_t)node*4096, S_acc, lane);
  } else {
    int wid = (b - 8)*8 + wave;                  // 0..127
    float part = 0.f;
    for(int p = 0; p < 4; p++){
      int gp = wid*4 + p;                        // 0..511 = (a,i)
      int a = gp >> 6, i = gp & 63;
      float ck = K[a*4096 + lane*64 + i];
      float t = 0.f;
      for(int m = 0; m < 64; m++){
        float cm = __shfl(ck, m, 64);
        t += rho_l[lane*64 + m] * cm;
      }
      float v = ck * t;
      for(int off = 32; off; off >>= 1) v += __shfl_xor(v, off, 64);
      part += v;
    }
    if(lane == 0) atomicAdd(mu_acc, part);
  }
}

// merged tail: 64 N2-nodes -> 8 (phase1, 8 waves) -> M (phase2) -> MFMA contraction.
// zones: 0-7 phase1 | 8 running/M | 9 rho_r | 10 rho_l | 11 U^T
__global__ __launch_bounds__(512) void k_tail(const u16* __restrict__ N2,
                                              const float* __restrict__ rho_r,
                                              const float* __restrict__ rho_l,
                                              const float* __restrict__ mu_p,
                                              const int* __restrict__ S_p,
                                              float* __restrict__ outp){
  __shared__ __align__(16) u16 zones[12*4096];
  __shared__ float dotp[8];
  __shared__ int exps[8];
  const int tid = threadIdx.x, lane = tid & 63, wave = tid >> 6;
  const int m16 = lane & 15, q = lane >> 4;

  // phase 0: rho_r -> zone9, rho_l -> zone10 (bf16 swizzled) + t2 partial dot
  float t2p = 0.f;
  {
    int row = tid >> 3, c0 = (tid & 7) * 8;
    int pos = row*64 + (((tid & 7) ^ (row & 7)) << 3);
    float pr[8], pl[8];
#pragma unroll
    for(int j = 0; j < 8; j++){ pr[j] = rho_r[row*64 + c0 + j]; pl[j] = rho_l[row*64 + c0 + j]; }
#pragma unroll
    for(int j = 0; j < 8; j++) t2p += pr[j]*pl[j];
    *(uint4*)(zones + 9*4096 + pos) = make_uint4(pack2bf(pr[0],pr[1]), pack2bf(pr[2],pr[3]),
                                                 pack2bf(pr[4],pr[5]), pack2bf(pr[6],pr[7]));
    *(uint4*)(zones + 10*4096 + pos) = make_uint4(pack2bf(pl[0],pl[1]), pack2bf(pl[2],pl[3]),
                                                  pack2bf(pl[4],pl[5]), pack2bf(pl[6],pl[7]));
  }
  for(int off = 32; off; off >>= 1) t2p += __shfl_xor(t2p, off, 64);
  if(lane == 0) dotp[wave] = t2p;

  // phase 1: 8 chains of 8 over N2; normalized result -> zone_w (as P_w^T)
  {
    u16* Pt = zones + wave*4096;
    f32x4 C[4][4];
    chain_loop(N2, nullptr, wave, 8, Pt, lane, C);
    float mx = 0.f;
#pragma unroll
    for(int i = 0; i < 4; i++)
#pragma unroll
      for(int j = 0; j < 4; j++)
#pragma unroll
        for(int t = 0; t < 4; t++) mx = fmaxf(mx, C[i][j][t]);
    mx = wave_max(mx);
    int e; (void)frexpf(mx, &e);
    write_CT_lds_s(Pt, lane, C, ldexpf(1.f, -e));
    if(lane == 0) exps[wave] = e;
  }
  __syncthreads();

  // phases 2+3 on wave 0 only
  if(wave == 0){
    u16* Pr = zones + 8*4096;
#pragma unroll
    for(int g = 0; g < 8; g++){                 // Pr <- transpose of zone7 content
      short8 f = lds_frag(zones + 7*4096, lane, g*8);
#pragma unroll
      for(int j = 0; j < 8; j++) Pr[swz(g*8 + j, lane)] = (u16)f[j];
    }
    f32x4 C[4][4];
#pragma unroll 1
    for(int w = 6; w >= 0; w--)
      chain_step_L(zones + w*4096, Pr, lane, C); // Pr content -> M (row-major swizzled)

    // step A: U = M * rho_r -> zone11 stores U^T
    short8 Aa[2][4], Bb[2][4];
#pragma unroll
    for(int ks = 0; ks < 2; ks++)
#pragma unroll
      for(int t = 0; t < 4; t++){
        Aa[ks][t] = lds_frag(Pr,               t*16 + m16, ks*32 + q*8);
        Bb[ks][t] = lds_frag(zones + 9*4096,   t*16 + m16, ks*32 + q*8);
      }
#pragma unroll
    for(int i = 0; i < 4; i++)
#pragma unroll
      for(int j = 0; j < 4; j++) C[i][j] = f32x4{0.f,0.f,0.f,0.f};
#pragma unroll
    for(int ks = 0; ks < 2; ks++)
#pragma unroll
      for(int i = 0; i < 4; i++)
#pragma unroll
        for(int j = 0; j < 4; j++)
          C[i][j] = mfma_bf16(Aa[ks][i], Bb[ks][j], C[i][j]);
    write_CT_lds(zones + 11*4096, lane, C);

    // step B: D2 = rho_l * U (SA = rho_l, SB = U^T stored)
#pragma unroll
    for(int ks = 0; ks < 2; ks++)
#pragma unroll
      for(int t = 0; t < 4; t++){
        Aa[ks][t] = lds_frag(zones + 10*4096, t*16 + m16, ks*32 + q*8);
        Bb[ks][t] = lds_frag(zones + 11*4096, t*16 + m16, ks*32 + q*8);
      }
#pragma unroll
    for(int i = 0; i < 4; i++)
#pragma unroll
      for(int j = 0; j < 4; j++) C[i][j] = f32x4{0.f,0.f,0.f,0.f};
#pragma unroll
    for(int ks = 0; ks < 2; ks++)
#pragma unroll
      for(int i = 0; i < 4; i++)
#pragma unroll
        for(int j = 0; j < 4; j++)
          C[i][j] = mfma_bf16(Aa[ks][i], Bb[ks][j], C[i][j]);

    // t1 = sum_ij D2_ij * M_ij
    float part = 0.f;
#pragma unroll
    for(int i = 0; i < 4; i++)
#pragma unroll
      for(int j = 0; j < 4; j++)
#pragma unroll
        for(int t = 0; t < 4; t++){
          int r = i*16 + q*4 + t, c = j*16 + m16;
          part += C[i][j][t] * bf2f(Pr[swz(r, c)]);
        }
    for(int off = 32; off; off >>= 1) part += __shfl_xor(part, off, 64);
    if(lane == 0){
      double t1 = (double)part;
      double t2 = 0.0;
      double S  = (double)(*S_p);
      for(int w = 0; w < 8; w++){ t2 += dotp[w]; S += exps[w]; }
      double lam = (double)(*mu_p);
      double logp = 16384.0*log2(lam) - 2.0*S - log2(t1) + log2(t2);
      outp[0] = (float)logp;
    }
  }
}

// ---------- launch ----------
extern "C" void kernel_launch(void* const* d_in, const int* in_sizes, int n_in,
                              void* d_out, int out_size, void* d_ws, size_t ws_size,
                              hipStream_t stream) {
  const float* K  = (const float*)d_in[0];   // (8,64,64) fp32
  const int* seq  = (const int*)d_in[1];     // (16384,) int32
  char* ws = (char*)d_ws;
  u16*   Kbf    = (u16*)(ws);                  // 65536
  u16*   KTbf   = (u16*)(ws + 65536);          // 65536
  float* rho_r  = (float*)(ws + 131072);       // 16384
  float* rho_l  = (float*)(ws + 147456);       // 16384
  int*   S_acc  = (int*)(ws + 163840);
  float* mu_acc = (float*)(ws + 163844);
  u16*   N1     = (u16*)(ws + 164352);         // 1024 * 8KB
  u16*   N2     = (u16*)(ws + 8552960);        // 64 * 8KB

  k_setup <<<128, 256, 0, stream>>>(K, Kbf, KTbf, S_acc, mu_acc);
  k_main  <<<130, 512, 0, stream>>>(Kbf, KTbf, seq, rho_r, rho_l, N1, S_acc);
  k_mid   <<<24,  512, 0, stream>>>(N1, N2, S_acc, K, rho_l, mu_acc);
  k_tail  <<<1,   512, 0, stream>>>(N2, rho_r, rho_l, mu_acc, S_acc, (float*)d_out);
}

// Round 5
// 141.091 us; speedup vs baseline: 1.2690x; 1.2690x over previous
//
#include <hip/hip_runtime.h>

typedef unsigned short u16;
typedef unsigned int   u32;
typedef short  short8  __attribute__((ext_vector_type(8)));
typedef __bf16 bf16x8  __attribute__((ext_vector_type(8)));
typedef float  f32x4   __attribute__((ext_vector_type(4)));
typedef u32    u32x4   __attribute__((ext_vector_type(4)));

#define POWER_ITERS 8

// ---------- helpers ----------
__device__ __forceinline__ u16 f2bf(float f){ return __builtin_bit_cast(u16, (__bf16)f); }
__device__ __forceinline__ u32 pack2bf(float a, float b){
  return (u32)__builtin_bit_cast(u16, (__bf16)a) | ((u32)__builtin_bit_cast(u16, (__bf16)b) << 16);
}
__device__ __forceinline__ float bf2f(u16 h){ return __uint_as_float(((u32)h) << 16); }

__device__ __forceinline__ f32x4 mfma_bf16(short8 a, short8 b, f32x4 c){
  return __builtin_amdgcn_mfma_f32_16x16x32_bf16(
      __builtin_bit_cast(bf16x8, a), __builtin_bit_cast(bf16x8, b), c, 0, 0, 0);
}

// swizzled LDS address (u16 units) of element [row][k] of a 64x64 matrix
__device__ __forceinline__ int swz(int row, int k){
  return row*64 + ((((k >> 3) ^ (row & 7)) << 3) | (k & 7));
}
__device__ __forceinline__ short8 lds_frag(const u16* P, int row, int k0){
  int pos = (k0 >> 3) ^ (row & 7);
  return *(const short8*)(P + row*64 + pos*8);
}
__device__ __forceinline__ short8 g_frag(const u16* __restrict__ M, int row, int k0){
  return *(const short8*)(M + row*64 + k0);
}

// write C/D regs (matrix X, C-layout) as X^T into swizzled LDS (bf16), scaled
__device__ __forceinline__ void write_CT_lds_s(u16* Pt, int lane, const f32x4 (&C)[4][4], float s){
  const int m16 = lane & 15, q = lane >> 4;
#pragma unroll
  for(int i = 0; i < 4; i++){
    const int r0 = i*16 + q*4;
#pragma unroll
    for(int j = 0; j < 4; j++){
      const int c = j*16 + m16;
      const int addr = c*64 + ((((r0 >> 3) ^ (c & 7)) << 3) | (r0 & 7));
      u32 lo = pack2bf(C[i][j][0]*s, C[i][j][1]*s);
      u32 hi = pack2bf(C[i][j][2]*s, C[i][j][3]*s);
      *(uint2*)(Pt + addr) = make_uint2(lo, hi);
    }
  }
}
__device__ __forceinline__ void write_CT_lds(u16* Pt, int lane, const f32x4 (&C)[4][4]){
  write_CT_lds_s(Pt, lane, C, 1.f);
}

// C = A (regs) * P (Pt holds P^T swizzled); optional writeback of C^T into Pt
__device__ __forceinline__ void chain_step_A(const short8 (&Af)[2][4], u16* Pt, int lane,
                                             f32x4 (&C)[4][4], bool wb){
  const int m16 = lane & 15, q = lane >> 4;
  short8 Bf[2][4];
#pragma unroll
  for(int ks = 0; ks < 2; ks++)
#pragma unroll
    for(int t = 0; t < 4; t++) Bf[ks][t] = lds_frag(Pt, t*16 + m16, ks*32 + q*8);
#pragma unroll
  for(int i = 0; i < 4; i++)
#pragma unroll
    for(int j = 0; j < 4; j++) C[i][j] = f32x4{0.f,0.f,0.f,0.f};
#pragma unroll
  for(int ks = 0; ks < 2; ks++)
#pragma unroll
    for(int i = 0; i < 4; i++)
#pragma unroll
      for(int j = 0; j < 4; j++)
        C[i][j] = mfma_bf16(Af[ks][i], Bf[ks][j], C[i][j]);
  if(wb) write_CT_lds(Pt, lane, C);
}

// A from LDS zone (row-major swizzled); writes C^T back into Pt
__device__ __forceinline__ void chain_step_L(const u16* Az, u16* Pt, int lane, f32x4 (&C)[4][4]){
  const int m16 = lane & 15, q = lane >> 4;
  short8 Af[2][4];
#pragma unroll
  for(int ks = 0; ks < 2; ks++)
#pragma unroll
    for(int t = 0; t < 4; t++) Af[ks][t] = lds_frag(Az, t*16 + m16, ks*32 + q*8);
  chain_step_A(Af, Pt, lane, C, true);
}

// P = N (global row-major bf16) -> store P^T swizzled
__device__ __forceinline__ void load_Pt_transpose(const u16* __restrict__ N, u16* Pt, int lane){
#pragma unroll
  for(int g = 0; g < 8; g++){
    short8 v = *(const short8*)(N + lane*64 + g*8);
#pragma unroll
    for(int t = 0; t < 8; t++) Pt[swz(g*8 + t, lane)] = (u16)v[t];
  }
}
// P = N (global row-major fp32) -> store P^T swizzled bf16
__device__ __forceinline__ void load_Pt_transpose_f32(const float* __restrict__ N, u16* Pt, int lane){
#pragma unroll
  for(int g = 0; g < 8; g++){
    float4 a = *(const float4*)(N + lane*64 + g*8);
    float4 b = *(const float4*)(N + lane*64 + g*8 + 4);
    Pt[swz(g*8 + 0, lane)] = f2bf(a.x); Pt[swz(g*8 + 1, lane)] = f2bf(a.y);
    Pt[swz(g*8 + 2, lane)] = f2bf(a.z); Pt[swz(g*8 + 3, lane)] = f2bf(a.w);
    Pt[swz(g*8 + 4, lane)] = f2bf(b.x); Pt[swz(g*8 + 5, lane)] = f2bf(b.y);
    Pt[swz(g*8 + 6, lane)] = f2bf(b.z); Pt[swz(g*8 + 7, lane)] = f2bf(b.w);
  }
}

// fp32 A-fragment prefetch (16 x float4) + convert to bf16 frags
__device__ __forceinline__ void ld_f32_frags(const float* __restrict__ Kp, int m16, int q,
                                             float4 (&F)[16]){
#pragma unroll
  for(int ks = 0; ks < 2; ks++)
#pragma unroll
    for(int t = 0; t < 4; t++){
      const float* p = Kp + (t*16 + m16)*64 + ks*32 + q*8;
      F[(ks*4 + t)*2]     = *(const float4*)p;
      F[(ks*4 + t)*2 + 1] = *(const float4*)(p + 4);
    }
}
__device__ __forceinline__ void cvt_frags(const float4 (&F)[16], short8 (&Af)[2][4]){
#pragma unroll
  for(int ks = 0; ks < 2; ks++)
#pragma unroll
    for(int t = 0; t < 4; t++){
      const float4& a = F[(ks*4 + t)*2];
      const float4& b = F[(ks*4 + t)*2 + 1];
      u32x4 u = { pack2bf(a.x,a.y), pack2bf(a.z,a.w), pack2bf(b.x,b.y), pack2bf(b.z,b.w) };
      Af[ks][t] = __builtin_bit_cast(short8, u);
    }
}

__device__ __forceinline__ float wave_max(float mx){
  for(int off = 32; off; off >>= 1) mx = fmaxf(mx, __shfl_xor(mx, off, 64));
  return mx;
}

// normalize C by power of 2, write X^T into zone; returns exponent
__device__ __forceinline__ int norm_write(const f32x4 (&C)[4][4], u16* zw, int lane){
  float mx = 0.f;
#pragma unroll
  for(int i = 0; i < 4; i++)
#pragma unroll
    for(int j = 0; j < 4; j++)
#pragma unroll
      for(int t = 0; t < 4; t++) mx = fmaxf(mx, C[i][j][t]);   // entries all positive
  mx = wave_max(mx);
  int e; (void)frexpf(mx, &e);
  write_CT_lds_s(zw, lane, C, ldexpf(1.f, -e));
  return e;
}

// sequential combine: zones 0..7 hold X_w^T; result Pr = X7*X6*...*X0 (row-major swizzled)
__device__ void combine8(u16* zones, u16* Pr, int lane){
#pragma unroll
  for(int g = 0; g < 8; g++){
    short8 f = lds_frag(zones + 7*4096, lane, g*8);
#pragma unroll
    for(int j = 0; j < 8; j++) Pr[swz(g*8 + j, lane)] = (u16)f[j];
  }
  f32x4 C[4][4];
#pragma unroll 1
  for(int w = 6; w >= 0; w--) chain_step_L(zones + w*4096, Pr, lane, C);
}

// write node (Pr, row-major swizzled) to global, fully coalesced (512 threads)
__device__ __forceinline__ void write_node(const u16* Pr, u16* __restrict__ out, int tid){
  int row = tid >> 3, c0 = (tid & 7) * 8;
  short8 v = lds_frag(Pr, row, c0);
  *(short8*)(out + row*64 + c0) = v;
}

// ---------- power iteration stages (one Kraus op per wave, K frags in regs) ----------
__device__ __forceinline__ void pw_stages(const short8 (&Kf)[2][4], const u16* rho, u16* zw,
                                          int m16, int q, int lane){
  short8 Ar[2][4];
#pragma unroll
  for(int ks = 0; ks < 2; ks++)
#pragma unroll
    for(int t = 0; t < 4; t++) Ar[ks][t] = lds_frag(rho, t*16 + m16, ks*32 + q*8);
  f32x4 C[4][4];
#pragma unroll
  for(int i = 0; i < 4; i++)
#pragma unroll
    for(int j = 0; j < 4; j++) C[i][j] = f32x4{0.f,0.f,0.f,0.f};
#pragma unroll
  for(int ks = 0; ks < 2; ks++)
#pragma unroll
    for(int i = 0; i < 4; i++)
#pragma unroll
      for(int j = 0; j < 4; j++)
        C[i][j] = mfma_bf16(Ar[ks][i], Kf[ks][j], C[i][j]);
  write_CT_lds(zw, lane, C);            // zw = Kw*rho (rho symmetric)
  short8 Bt[2][4];
#pragma unroll
  for(int ks = 0; ks < 2; ks++)
#pragma unroll
    for(int t = 0; t < 4; t++) Bt[ks][t] = lds_frag(zw, t*16 + m16, ks*32 + q*8);
#pragma unroll
  for(int i = 0; i < 4; i++)
#pragma unroll
    for(int j = 0; j < 4; j++) C[i][j] = f32x4{0.f,0.f,0.f,0.f};
#pragma unroll
  for(int ks = 0; ks < 2; ks++)
#pragma unroll
    for(int i = 0; i < 4; i++)
#pragma unroll
      for(int j = 0; j < 4; j++)
        C[i][j] = mfma_bf16(Kf[ks][i], Bt[ks][j], C[i][j]);
  write_CT_lds(zw, lane, C);            // zone_w = Kw*rho*Kw^T
}

// ---------- k1: blocks 0,1 power iteration; blocks 2..257 tree level 1 (64 mats -> 1 node) ----------
__global__ __launch_bounds__(512, 2) void k1(const float* __restrict__ K, const int* __restrict__ seq,
                                             float* __restrict__ rho_r, float* __restrict__ rho_l,
                                             u16* __restrict__ N1, int* __restrict__ Sarr){
  __shared__ __align__(16) u16 zbuf[9*4096];
  __shared__ float red[8];
  __shared__ int exps[8];
  const int tid = threadIdx.x, lane = tid & 63, wave = tid >> 6, b = blockIdx.x;
  const int m16 = lane & 15, q = lane >> 4;
  u16* zw = zbuf + wave*4096;

  if(b < 2){
    // stage K[wave] fp32 -> zw (bf16 row-major swizzled); lane owns row=lane
#pragma unroll
    for(int g = 0; g < 8; g++){
      const float* p = K + (size_t)wave*4096 + lane*64 + g*8;
      float4 a = *(const float4*)p, c = *(const float4*)(p + 4);
      u32x4 u = { pack2bf(a.x,a.y), pack2bf(a.z,a.w), pack2bf(c.x,c.y), pack2bf(c.z,c.w) };
      *(short8*)(zw + lane*64 + ((g ^ (lane & 7)) << 3)) = __builtin_bit_cast(short8, u);
    }
    short8 Kf[2][4];
    if(b == 0){                          // right: rows of K_a
#pragma unroll
      for(int ks = 0; ks < 2; ks++)
#pragma unroll
        for(int t = 0; t < 4; t++) Kf[ks][t] = lds_frag(zw, t*16 + m16, ks*32 + q*8);
    } else {                             // left: rows of K_a^T (column walk)
#pragma unroll
      for(int ks = 0; ks < 2; ks++)
#pragma unroll
        for(int t = 0; t < 4; t++){
          short8 v;
#pragma unroll
          for(int j = 0; j < 8; j++) v[j] = (short)zw[swz(ks*32 + q*8 + j, t*16 + m16)];
          Kf[ks][t] = v;
        }
    }
    u16* rho = zbuf + 8*4096;
    const int row = tid >> 3, k0 = (tid & 7) * 8;
    const int rpos = row*64 + (((tid & 7) ^ (row & 7)) << 3);
    {
      short8 bb;
#pragma unroll
      for(int j = 0; j < 8; j++) bb[j] = (row == k0 + j) ? (short)f2bf(1.f/64.f) : (short)0;
      *(short8*)(rho + rpos) = bb;
    }
    __syncthreads();
    const float S13 = 1.f/8192.f;        // fixed per-iter scale (lambda ~ 2^13)
#pragma unroll 1
    for(int it = 0; it < POWER_ITERS; it++){
      pw_stages(Kf, rho, zw, m16, q, lane);
      __syncthreads();
      float v[8];
#pragma unroll
      for(int j = 0; j < 8; j++) v[j] = 0.f;
#pragma unroll
      for(int z = 0; z < 8; z++){
        short8 f = lds_frag(zbuf + z*4096, row, k0);
#pragma unroll
        for(int j = 0; j < 8; j++) v[j] += bf2f((u16)f[j]);
      }
      if(it != POWER_ITERS - 1){
        u32x4 u = { pack2bf(v[0]*S13, v[1]*S13), pack2bf(v[2]*S13, v[3]*S13),
                    pack2bf(v[4]*S13, v[5]*S13), pack2bf(v[6]*S13, v[7]*S13) };
        *(short8*)(rho + rpos) = __builtin_bit_cast(short8, u);
        __syncthreads();
      } else {
        float pd = (k0 <= row && row < k0 + 8) ? v[row - k0] : 0.f;
        for(int off = 32; off; off >>= 1) pd += __shfl_xor(pd, off, 64);
        if(lane == 0) red[wave] = pd;
        __syncthreads();
        float tr = 0.f;
#pragma unroll
        for(int w = 0; w < 8; w++) tr += red[w];
        float inv = 1.f / tr;
        float* ro = (b == 0) ? rho_r : rho_l;
#pragma unroll
        for(int j = 0; j < 8; j++) ro[row*64 + k0 + j] = v[j] * inv;
      }
    }
  } else {
    const int node = b - 2;
    int sv = (lane < 8) ? seq[node*64 + wave*8 + lane] : 0;
    int s0 = __shfl(sv, 0, 64), s1 = __shfl(sv, 1, 64);
    float4 F[16];
    ld_f32_frags(K + (size_t)s1*4096, m16, q, F);
    load_Pt_transpose_f32(K + (size_t)s0*4096, zw, lane);
    f32x4 C[4][4];
    short8 Af[2][4];
#pragma unroll 1
    for(int j = 1; j < 8; j++){
      cvt_frags(F, Af);
      if(j < 7){
        int sn = __shfl(sv, j + 1, 64);
        ld_f32_frags(K + (size_t)sn*4096, m16, q, F);
      }
      chain_step_A(Af, zw, lane, C, j < 7);
    }
    int e = norm_write(C, zw, lane);
    if(lane == 0) exps[wave] = e;
    __syncthreads();
    if(wave == 0) combine8(zbuf, zbuf + 8*4096, lane);
    __syncthreads();
    write_node(zbuf + 8*4096, N1 + (size_t)node*4096, tid);
    if(tid == 0){
      int s = 0;
#pragma unroll
      for(int w = 0; w < 8; w++) s += exps[w];
      Sarr[node] = s;
    }
  }
}

// ---------- k2: blocks 0..15 tree level 2 (16 nodes -> 1); blocks 16..31 fp32 Rayleigh ----------
__global__ __launch_bounds__(512, 2) void k2(const u16* __restrict__ N1, u16* __restrict__ N2,
                                             int* __restrict__ Earr, const float* __restrict__ K,
                                             const float* __restrict__ rho_l,
                                             float* __restrict__ muarr){
  __shared__ __align__(16) u16 zbuf[9*4096];
  __shared__ int exps[8];
  const int tid = threadIdx.x, lane = tid & 63, wave = tid >> 6, b = blockIdx.x;
  const int m16 = lane & 15, q = lane >> 4;
  if(b < 16){
    u16* zw = zbuf + wave*4096;
    const int n0 = b*16 + wave*2;
    short8 Af[2][4];
#pragma unroll
    for(int ks = 0; ks < 2; ks++)
#pragma unroll
      for(int t = 0; t < 4; t++)
        Af[ks][t] = g_frag(N1 + (size_t)(n0 + 1)*4096, t*16 + m16, ks*32 + q*8);
    load_Pt_transpose(N1 + (size_t)n0*4096, zw, lane);
    f32x4 C[4][4];
    chain_step_A(Af, zw, lane, C, false);
    int e = norm_write(C, zw, lane);
    if(lane == 0) exps[wave] = e;
    __syncthreads();
    if(wave == 0) combine8(zbuf, zbuf + 8*4096, lane);
    __syncthreads();
    write_node(zbuf + 8*4096, N2 + (size_t)b*4096, tid);
    if(tid == 0){
      int s = 0;
#pragma unroll
      for(int w = 0; w < 8; w++) s += exps[w];
      Earr[b] = s;
    }
  } else {
    int wid = (b - 16)*8 + wave;                 // 0..127
    float part = 0.f;
    for(int p = 0; p < 4; p++){
      int gp = wid*4 + p;                        // 0..511 = (a,i)
      int a = gp >> 6, i = gp & 63;
      float ck = K[a*4096 + lane*64 + i];
      float t = 0.f;
      for(int m = 0; m < 64; m++){
        float cm = __shfl(ck, m, 64);
        t += rho_l[lane*64 + m] * cm;
      }
      float v = ck * t;
      for(int off = 32; off; off >>= 1) v += __shfl_xor(v, off, 64);
      part += v;
    }
    if(lane == 0) muarr[wid] = part;
  }
}

// ---------- k3: 16 nodes -> M; contraction; logp ----------
// zones: 0-7 wave products | 8 Pr/M | 9 rho_r | 10 rho_l | 11 U^T
__global__ __launch_bounds__(512, 2) void k3(const u16* __restrict__ N2,
                                             const float* __restrict__ rho_r,
                                             const float* __restrict__ rho_l,
                                             const float* __restrict__ muarr,
                                             const int* __restrict__ Sarr,
                                             const int* __restrict__ Earr,
                                             float* __restrict__ outp){
  __shared__ __align__(16) u16 zbuf[12*4096];
  __shared__ float dotp[8];
  __shared__ int exps[8];
  __shared__ float mu_s;
  __shared__ int sS_s;
  const int tid = threadIdx.x, lane = tid & 63, wave = tid >> 6;
  const int m16 = lane & 15, q = lane >> 4;
  u16* zw = zbuf + wave*4096;

  // prefetch phase-1 A operand first (global)
  short8 Af[2][4];
#pragma unroll
  for(int ks = 0; ks < 2; ks++)
#pragma unroll
    for(int t = 0; t < 4; t++)
      Af[ks][t] = g_frag(N2 + (size_t)(wave*2 + 1)*4096, t*16 + m16, ks*32 + q*8);

  // phase 0: stage rho_r -> zone9, rho_l -> zone10 (bf16 swizzled) + t2 partial
  float t2p = 0.f;
  {
    int row = tid >> 3, c0 = (tid & 7) * 8;
    int pos = row*64 + (((tid & 7) ^ (row & 7)) << 3);
    float pr[8], pl[8];
#pragma unroll
    for(int j = 0; j < 8; j++){ pr[j] = rho_r[row*64 + c0 + j]; pl[j] = rho_l[row*64 + c0 + j]; }
#pragma unroll
    for(int j = 0; j < 8; j++) t2p += pr[j]*pl[j];
    u32x4 ur = { pack2bf(pr[0],pr[1]), pack2bf(pr[2],pr[3]), pack2bf(pr[4],pr[5]), pack2bf(pr[6],pr[7]) };
    u32x4 ul = { pack2bf(pl[0],pl[1]), pack2bf(pl[2],pl[3]), pack2bf(pl[4],pl[5]), pack2bf(pl[6],pl[7]) };
    *(short8*)(zbuf + 9*4096 + pos)  = __builtin_bit_cast(short8, ur);
    *(short8*)(zbuf + 10*4096 + pos) = __builtin_bit_cast(short8, ul);
  }
  for(int off = 32; off; off >>= 1) t2p += __shfl_xor(t2p, off, 64);
  if(lane == 0) dotp[wave] = t2p;

  // phase 1: wave w: X_w = N2[2w+1]*N2[2w]
  load_Pt_transpose(N2 + (size_t)(wave*2)*4096, zw, lane);
  f32x4 C[4][4];
  chain_step_A(Af, zw, lane, C, false);
  int e = norm_write(C, zw, lane);
  if(lane == 0) exps[wave] = e;
  __syncthreads();

  // phase 2: wave0 combines -> M; wave1/wave2 sum exponent/lambda arrays
  if(wave == 0){
    combine8(zbuf, zbuf + 8*4096, lane);
  } else if(wave == 1){
    int s = Sarr[lane] + Sarr[lane + 64] + Sarr[lane + 128] + Sarr[lane + 192];
    if(lane < 16) s += Earr[lane];
    for(int off = 32; off; off >>= 1) s += __shfl_xor(s, off, 64);
    if(lane == 0) sS_s = s;
  } else if(wave == 2){
    float m = muarr[lane] + muarr[lane + 64];
    for(int off = 32; off; off >>= 1) m += __shfl_xor(m, off, 64);
    if(lane == 0) mu_s = m;
  }
  __syncthreads();

  // phase 3: contraction t1 = tr(M rho_r M^T rho_l) via MFMA (wave 0)
  if(wave == 0){
    u16* Pr = zbuf + 8*4096;
    short8 Aa[2][4], Bb[2][4];
#pragma unroll
    for(int ks = 0; ks < 2; ks++)
#pragma unroll
      for(int t = 0; t < 4; t++){
        Aa[ks][t] = lds_frag(Pr,              t*16 + m16, ks*32 + q*8);
        Bb[ks][t] = lds_frag(zbuf + 9*4096,   t*16 + m16, ks*32 + q*8);
      }
#pragma unroll
    for(int i = 0; i < 4; i++)
#pragma unroll
      for(int j = 0; j < 4; j++) C[i][j] = f32x4{0.f,0.f,0.f,0.f};
#pragma unroll
    for(int ks = 0; ks < 2; ks++)
#pragma unroll
      for(int i = 0; i < 4; i++)
#pragma unroll
        for(int j = 0; j < 4; j++)
          C[i][j] = mfma_bf16(Aa[ks][i], Bb[ks][j], C[i][j]);
    write_CT_lds(zbuf + 11*4096, lane, C);       // U^T, U = M*rho_r

#pragma unroll
    for(int ks = 0; ks < 2; ks++)
#pragma unroll
      for(int t = 0; t < 4; t++){
        Aa[ks][t] = lds_frag(zbuf + 10*4096, t*16 + m16, ks*32 + q*8);
        Bb[ks][t] = lds_frag(zbuf + 11*4096, t*16 + m16, ks*32 + q*8);
      }
#pragma unroll
    for(int i = 0; i < 4; i++)
#pragma unroll
      for(int j = 0; j < 4; j++) C[i][j] = f32x4{0.f,0.f,0.f,0.f};
#pragma unroll
    for(int ks = 0; ks < 2; ks++)
#pragma unroll
      for(int i = 0; i < 4; i++)
#pragma unroll
        for(int j = 0; j < 4; j++)
          C[i][j] = mfma_bf16(Aa[ks][i], Bb[ks][j], C[i][j]);  // D2 = rho_l * U

    float part = 0.f;
#pragma unroll
    for(int i = 0; i < 4; i++)
#pragma unroll
      for(int j = 0; j < 4; j++)
#pragma unroll
        for(int t = 0; t < 4; t++){
          int r = i*16 + q*4 + t, c = j*16 + m16;
          part += C[i][j][t] * bf2f(Pr[swz(r, c)]);
        }
    for(int off = 32; off; off >>= 1) part += __shfl_xor(part, off, 64);
    if(lane == 0){
      double t1 = (double)part;
      double t2 = 0.0;
      int S = sS_s;
#pragma unroll
      for(int w = 0; w < 8; w++){ t2 += dotp[w]; S += exps[w]; }
      double lam = (double)mu_s;
      double logp = 16384.0*log2(lam) - 2.0*(double)S - log2(t1) + log2(t2);
      outp[0] = (float)logp;
    }
  }
}

// ---------- launch ----------
extern "C" void kernel_launch(void* const* d_in, const int* in_sizes, int n_in,
                              void* d_out, int out_size, void* d_ws, size_t ws_size,
                              hipStream_t stream) {
  const float* K  = (const float*)d_in[0];   // (8,64,64) fp32
  const int* seq  = (const int*)d_in[1];     // (16384,) int32
  char* ws = (char*)d_ws;
  u16*   N1    = (u16*)(ws);                   // 256 * 8KB = 2 MB
  u16*   N2    = (u16*)(ws + 2097152);         // 16 * 8KB = 128 KB
  float* rho_r = (float*)(ws + 2228224);       // 16 KB
  float* rho_l = (float*)(ws + 2244608);       // 16 KB
  int*   Sarr  = (int*)(ws + 2260992);         // 256 ints
  int*   Earr  = (int*)(ws + 2262016);         // 16 ints
  float* muarr = (float*)(ws + 2262528);       // 128 floats

  k1<<<258, 512, 0, stream>>>(K, seq, rho_r, rho_l, N1, Sarr);
  k2<<<32,  512, 0, stream>>>(N1, N2, Earr, K, rho_l, muarr);
  k3<<<1,   512, 0, stream>>>(N2, rho_r, rho_l, muarr, Sarr, Earr, (float*)d_out);
}

// Round 6
// 138.594 us; speedup vs baseline: 1.2918x; 1.0180x over previous
//
#include <hip/hip_runtime.h>

typedef unsigned short u16;
typedef unsigned int   u32;
typedef short  short8  __attribute__((ext_vector_type(8)));
typedef __bf16 bf16x8  __attribute__((ext_vector_type(8)));
typedef float  f32x4   __attribute__((ext_vector_type(4)));
typedef u32    u32x4   __attribute__((ext_vector_type(4)));

#define POWER_ITERS 3

// ---------- helpers ----------
__device__ __forceinline__ u16 f2bf(float f){ return __builtin_bit_cast(u16, (__bf16)f); }
__device__ __forceinline__ u32 pack2bf(float a, float b){
  return (u32)__builtin_bit_cast(u16, (__bf16)a) | ((u32)__builtin_bit_cast(u16, (__bf16)b) << 16);
}
__device__ __forceinline__ float bf2f(u16 h){ return __uint_as_float(((u32)h) << 16); }

__device__ __forceinline__ f32x4 mfma_bf16(short8 a, short8 b, f32x4 c){
  return __builtin_amdgcn_mfma_f32_16x16x32_bf16(
      __builtin_bit_cast(bf16x8, a), __builtin_bit_cast(bf16x8, b), c, 0, 0, 0);
}

// swizzled LDS address (u16 units) of element [row][k] of a 64x64 matrix
__device__ __forceinline__ int swz(int row, int k){
  return row*64 + ((((k >> 3) ^ (row & 7)) << 3) | (k & 7));
}
__device__ __forceinline__ short8 lds_frag(const u16* P, int row, int k0){
  int pos = (k0 >> 3) ^ (row & 7);
  return *(const short8*)(P + row*64 + pos*8);
}
__device__ __forceinline__ short8 g_frag(const u16* __restrict__ M, int row, int k0){
  return *(const short8*)(M + row*64 + k0);
}

// write C/D regs (matrix X, C-layout) as X^T into swizzled LDS (Zt format), scaled
__device__ __forceinline__ void write_CT_lds_s(u16* Pt, int lane, const f32x4 (&C)[4][4], float s){
  const int m16 = lane & 15, q = lane >> 4;
#pragma unroll
  for(int i = 0; i < 4; i++){
    const int r0 = i*16 + q*4;
#pragma unroll
    for(int j = 0; j < 4; j++){
      const int c = j*16 + m16;
      const int addr = c*64 + ((((r0 >> 3) ^ (c & 7)) << 3) | (r0 & 7));
      u32 lo = pack2bf(C[i][j][0]*s, C[i][j][1]*s);
      u32 hi = pack2bf(C[i][j][2]*s, C[i][j][3]*s);
      *(uint2*)(Pt + addr) = make_uint2(lo, hi);
    }
  }
}
__device__ __forceinline__ void write_CT_lds(u16* Pt, int lane, const f32x4 (&C)[4][4]){
  write_CT_lds_s(Pt, lane, C, 1.f);
}

// write C (matrix X, C-layout) ROW-MAJOR swizzled (Zn format), scaled — scalar scatter
__device__ __forceinline__ void scatter_C_rm(u16* Z, int lane, const f32x4 (&C)[4][4], float s){
  const int m16 = lane & 15, q = lane >> 4;
#pragma unroll
  for(int i = 0; i < 4; i++)
#pragma unroll
    for(int j = 0; j < 4; j++)
#pragma unroll
      for(int t = 0; t < 4; t++)
        Z[swz(i*16 + q*4 + t, j*16 + m16)] = f2bf(C[i][j][t]*s);
}

// C = A (regs) * P (Pt = Zt of P); optional write of C^T back into Pt
__device__ __forceinline__ void chain_step_A(const short8 (&Af)[2][4], u16* Pt, int lane,
                                             f32x4 (&C)[4][4], bool wb){
  const int m16 = lane & 15, q = lane >> 4;
  short8 Bf[2][4];
#pragma unroll
  for(int ks = 0; ks < 2; ks++)
#pragma unroll
    for(int t = 0; t < 4; t++) Bf[ks][t] = lds_frag(Pt, t*16 + m16, ks*32 + q*8);
#pragma unroll
  for(int i = 0; i < 4; i++)
#pragma unroll
    for(int j = 0; j < 4; j++) C[i][j] = f32x4{0.f,0.f,0.f,0.f};
#pragma unroll
  for(int ks = 0; ks < 2; ks++)
#pragma unroll
    for(int i = 0; i < 4; i++)
#pragma unroll
      for(int j = 0; j < 4; j++)
        C[i][j] = mfma_bf16(Af[ks][i], Bf[ks][j], C[i][j]);
  if(wb) write_CT_lds(Pt, lane, C);
}

// A-frags (rows) from a Zn-format LDS zone
__device__ __forceinline__ void ld_zn_frags(const u16* Zn, int m16, int q, short8 (&Af)[2][4]){
#pragma unroll
  for(int ks = 0; ks < 2; ks++)
#pragma unroll
    for(int t = 0; t < 4; t++) Af[ks][t] = lds_frag(Zn, t*16 + m16, ks*32 + q*8);
}
// A-frags from row-major bf16 global
__device__ __forceinline__ void ld_bf16_frags(const u16* __restrict__ M, int m16, int q, short8 (&Af)[2][4]){
#pragma unroll
  for(int ks = 0; ks < 2; ks++)
#pragma unroll
    for(int t = 0; t < 4; t++) Af[ks][t] = g_frag(M, t*16 + m16, ks*32 + q*8);
}
// A-frags from row-major fp32 global, fused convert (low reg pressure)
__device__ __forceinline__ void ld_cvt_frags(const float* __restrict__ Kp, int m16, int q, short8 (&Af)[2][4]){
#pragma unroll
  for(int ks = 0; ks < 2; ks++)
#pragma unroll
    for(int t = 0; t < 4; t++){
      const float* p = Kp + (t*16 + m16)*64 + ks*32 + q*8;
      float4 a = *(const float4*)p, b = *(const float4*)(p + 4);
      u32x4 u = { pack2bf(a.x,a.y), pack2bf(a.z,a.w), pack2bf(b.x,b.y), pack2bf(b.z,b.w) };
      Af[ks][t] = __builtin_bit_cast(short8, u);
    }
}

// P = N (global row-major bf16) -> Zt of P
__device__ __forceinline__ void load_Pt_transpose(const u16* __restrict__ N, u16* Pt, int lane){
#pragma unroll
  for(int g = 0; g < 8; g++){
    short8 v = *(const short8*)(N + lane*64 + g*8);
#pragma unroll
    for(int t = 0; t < 8; t++) Pt[swz(g*8 + t, lane)] = (u16)v[t];
  }
}
// P = N (global row-major fp32) -> Zt of P (bf16)
__device__ __forceinline__ void load_Pt_transpose_f32(const float* __restrict__ N, u16* Pt, int lane){
#pragma unroll
  for(int g = 0; g < 8; g++){
    float4 a = *(const float4*)(N + lane*64 + g*8);
    float4 b = *(const float4*)(N + lane*64 + g*8 + 4);
    Pt[swz(g*8 + 0, lane)] = f2bf(a.x); Pt[swz(g*8 + 1, lane)] = f2bf(a.y);
    Pt[swz(g*8 + 2, lane)] = f2bf(a.z); Pt[swz(g*8 + 3, lane)] = f2bf(a.w);
    Pt[swz(g*8 + 4, lane)] = f2bf(b.x); Pt[swz(g*8 + 5, lane)] = f2bf(b.y);
    Pt[swz(g*8 + 6, lane)] = f2bf(b.z); Pt[swz(g*8 + 7, lane)] = f2bf(b.w);
  }
}

__device__ __forceinline__ float wave_max(float mx){
  for(int off = 32; off; off >>= 1) mx = fmaxf(mx, __shfl_xor(mx, off, 64));
  return mx;
}
// power-of-2 norm: returns exponent, sets scale
__device__ __forceinline__ int norm_es(const f32x4 (&C)[4][4], float& s){
  float mx = 0.f;
#pragma unroll
  for(int i = 0; i < 4; i++)
#pragma unroll
    for(int j = 0; j < 4; j++)
#pragma unroll
      for(int t = 0; t < 4; t++) mx = fmaxf(mx, C[i][j][t]);   // entries all positive
  mx = wave_max(mx);
  int e; (void)frexpf(mx, &e);
  s = ldexpf(1.f, -e);
  return e;
}

// ---------- k1: 1024 blocks x 256 thr; block = 16 seq-matrices -> one node ----------
__global__ __launch_bounds__(256) void k1(const float* __restrict__ K, const int* __restrict__ seq,
                                          u16* __restrict__ N1, int* __restrict__ Sarr){
  __shared__ __align__(16) u16 zbuf[4*4096];
  const int tid = threadIdx.x, lane = tid & 63, wave = tid >> 6, b = blockIdx.x;
  const int m16 = lane & 15, q = lane >> 4;
  u16* zw = zbuf + wave*4096;

  int sv = (lane < 4) ? seq[b*16 + wave*4 + lane] : 0;
  const int s0 = __shfl(sv, 0, 64), s1 = __shfl(sv, 1, 64);
  const int s2 = __shfl(sv, 2, 64), s3 = __shfl(sv, 3, 64);

  short8 Af[2][4];
  f32x4 C[4][4];
  load_Pt_transpose_f32(K + (size_t)s0*4096, zw, lane);
  ld_cvt_frags(K + (size_t)s1*4096, m16, q, Af);
  chain_step_A(Af, zw, lane, C, true);
  ld_cvt_frags(K + (size_t)s2*4096, m16, q, Af);
  chain_step_A(Af, zw, lane, C, true);
  ld_cvt_frags(K + (size_t)s3*4096, m16, q, Af);
  const bool ev = !(wave & 1);
  chain_step_A(Af, zw, lane, C, ev);          // even wave -> Zt in zone w
  if(!ev) scatter_C_rm(zw, lane, C, 1.f);     // odd wave -> Zn in zone w
  __syncthreads();

  // combine level 1: wave w in {0,1}: Y_w = X_{2w+1}(Zn) * X_{2w}(Zt) -> zone 2w
  if(wave < 2){
    short8 Aa[2][4];
    ld_zn_frags(zbuf + (2*wave + 1)*4096, m16, q, Aa);
    f32x4 Y[4][4];
    chain_step_A(Aa, zbuf + 2*wave*4096, lane, Y, wave == 0);   // wave0 -> Zt zone0
    if(wave == 1) scatter_C_rm(zbuf + 2*4096, lane, Y, 1.f);    // wave1 -> Zn zone2
  }
  __syncthreads();

  // combine level 2 (wave 0): M = Y1(Zn z2) * Y0(Zt z0); normalize; Zn -> zone0
  if(wave == 0){
    short8 Aa[2][4];
    ld_zn_frags(zbuf + 2*4096, m16, q, Aa);
    f32x4 M[4][4];
    chain_step_A(Aa, zbuf, lane, M, false);
    float s; int e = norm_es(M, s);
    scatter_C_rm(zbuf, lane, M, s);
    if(lane == 0) Sarr[b] = e;
  }
  __syncthreads();

  // coalesced node write: 256 threads x 32B
  {
    int row = tid >> 2, c0 = (tid & 3)*16;
    short8 v0 = lds_frag(zbuf, row, c0);
    short8 v1 = lds_frag(zbuf, row, c0 + 8);
    u16* out = N1 + (size_t)b*4096 + row*64 + c0;
    *(short8*)out = v0;
    *(short8*)(out + 8) = v1;
  }
}

// ---------- k2: b0,b1 power iteration; b2..65: 16 N1-nodes -> one N2 node ----------
__global__ __launch_bounds__(512) void k2(const float* __restrict__ K, const u16* __restrict__ N1,
                                          u16* __restrict__ N2, int* __restrict__ Earr,
                                          float* __restrict__ rho_r, float* __restrict__ rho_l){
  __shared__ __align__(16) u16 zbuf[9*4096];
  __shared__ float red[8];
  const int tid = threadIdx.x, lane = tid & 63, wave = tid >> 6, b = blockIdx.x;
  const int m16 = lane & 15, q = lane >> 4;
  u16* zw = zbuf + wave*4096;

  if(b < 2){
    // ---- power iteration: 8 waves, one Kraus op per wave, K frags in regs ----
    // stage K[wave] fp32 -> zw (bf16 row-major swizzled)
#pragma unroll
    for(int g = 0; g < 8; g++){
      const float* p = K + (size_t)wave*4096 + lane*64 + g*8;
      float4 a = *(const float4*)p, c = *(const float4*)(p + 4);
      u32x4 u = { pack2bf(a.x,a.y), pack2bf(a.z,a.w), pack2bf(c.x,c.y), pack2bf(c.z,c.w) };
      *(short8*)(zw + lane*64 + ((g ^ (lane & 7)) << 3)) = __builtin_bit_cast(short8, u);
    }
    short8 Kf[2][4];
    if(b == 0){                          // right: rows of K_a
#pragma unroll
      for(int ks = 0; ks < 2; ks++)
#pragma unroll
        for(int t = 0; t < 4; t++) Kf[ks][t] = lds_frag(zw, t*16 + m16, ks*32 + q*8);
    } else {                             // left: rows of K_a^T (column walk)
#pragma unroll
      for(int ks = 0; ks < 2; ks++)
#pragma unroll
        for(int t = 0; t < 4; t++){
          short8 v;
#pragma unroll
          for(int j = 0; j < 8; j++) v[j] = (short)zw[swz(ks*32 + q*8 + j, t*16 + m16)];
          Kf[ks][t] = v;
        }
    }
    u16* rho = zbuf + 8*4096;
    const int row = tid >> 3, k0 = (tid & 7) * 8;
    const int rpos = row*64 + (((tid & 7) ^ (row & 7)) << 3);
    {
      short8 bb;
#pragma unroll
      for(int j = 0; j < 8; j++) bb[j] = (row == k0 + j) ? (short)f2bf(1.f/64.f) : (short)0;
      *(short8*)(rho + rpos) = bb;
    }
    __syncthreads();
    const float S13 = 1.f/8192.f;        // fixed per-iter scale (lambda ~ 2^13)
#pragma unroll
    for(int it = 0; it < POWER_ITERS; it++){
      // stage 1: C = rho * Kw^T  (rho symmetric)
      short8 Ar[2][4];
#pragma unroll
      for(int ks = 0; ks < 2; ks++)
#pragma unroll
        for(int t = 0; t < 4; t++) Ar[ks][t] = lds_frag(rho, t*16 + m16, ks*32 + q*8);
      f32x4 C[4][4];
#pragma unroll
      for(int i = 0; i < 4; i++)
#pragma unroll
        for(int j = 0; j < 4; j++) C[i][j] = f32x4{0.f,0.f,0.f,0.f};
#pragma unroll
      for(int ks = 0; ks < 2; ks++)
#pragma unroll
        for(int i = 0; i < 4; i++)
#pragma unroll
          for(int j = 0; j < 4; j++)
            C[i][j] = mfma_bf16(Ar[ks][i], Kf[ks][j], C[i][j]);
      write_CT_lds(zw, lane, C);          // zw = Kw*rho
      // stage 2: C = Kw * (Kw*rho)^T
      short8 Bt[2][4];
#pragma unroll
      for(int ks = 0; ks < 2; ks++)
#pragma unroll
        for(int t = 0; t < 4; t++) Bt[ks][t] = lds_frag(zw, t*16 + m16, ks*32 + q*8);
#pragma unroll
      for(int i = 0; i < 4; i++)
#pragma unroll
        for(int j = 0; j < 4; j++) C[i][j] = f32x4{0.f,0.f,0.f,0.f};
#pragma unroll
      for(int ks = 0; ks < 2; ks++)
#pragma unroll
        for(int i = 0; i < 4; i++)
#pragma unroll
          for(int j = 0; j < 4; j++)
            C[i][j] = mfma_bf16(Kf[ks][i], Bt[ks][j], C[i][j]);
      write_CT_lds(zw, lane, C);
      __syncthreads();
      float v[8];
#pragma unroll
      for(int j = 0; j < 8; j++) v[j] = 0.f;
#pragma unroll
      for(int z = 0; z < 8; z++){
        short8 f = lds_frag(zbuf + z*4096, row, k0);
#pragma unroll
        for(int j = 0; j < 8; j++) v[j] += bf2f((u16)f[j]);
      }
      if(it != POWER_ITERS - 1){
        u32x4 u = { pack2bf(v[0]*S13, v[1]*S13), pack2bf(v[2]*S13, v[3]*S13),
                    pack2bf(v[4]*S13, v[5]*S13), pack2bf(v[6]*S13, v[7]*S13) };
        *(short8*)(rho + rpos) = __builtin_bit_cast(short8, u);
        __syncthreads();
      } else {
        float pd = (k0 <= row && row < k0 + 8) ? v[row - k0] : 0.f;
        for(int off = 32; off; off >>= 1) pd += __shfl_xor(pd, off, 64);
        if(lane == 0) red[wave] = pd;
        __syncthreads();
        float tr = 0.f;
#pragma unroll
        for(int w = 0; w < 8; w++) tr += red[w];
        float inv = 1.f / tr;
        float* ro = (b == 0) ? rho_r : rho_l;
#pragma unroll
        for(int j = 0; j < 8; j++) ro[row*64 + k0 + j] = v[j] * inv;
      }
    }
  } else {
    // ---- level-2 chains: node = N1[nb+15]...N1[nb] ----
    const int nb = (b - 2)*16;
    short8 Af[2][4];
    ld_bf16_frags(N1 + (size_t)(nb + 2*wave + 1)*4096, m16, q, Af);
    load_Pt_transpose(N1 + (size_t)(nb + 2*wave)*4096, zw, lane);
    f32x4 C[4][4];
    bool ev = !(wave & 1);
    chain_step_A(Af, zw, lane, C, ev);
    if(!ev) scatter_C_rm(zw, lane, C, 1.f);
    __syncthreads();
    if(wave < 4){
      short8 Aa[2][4];
      ld_zn_frags(zbuf + (2*wave + 1)*4096, m16, q, Aa);
      f32x4 Y[4][4];
      bool e2 = !(wave & 1);
      chain_step_A(Aa, zbuf + 2*wave*4096, lane, Y, e2);
      if(!e2) scatter_C_rm(zbuf + 2*wave*4096, lane, Y, 1.f);
    }
    __syncthreads();
    if(wave < 2){
      short8 Aa[2][4];
      ld_zn_frags(zbuf + (4*wave + 2)*4096, m16, q, Aa);
      f32x4 Y[4][4];
      chain_step_A(Aa, zbuf + 4*wave*4096, lane, Y, wave == 0);
      if(wave == 1) scatter_C_rm(zbuf + 4*4096, lane, Y, 1.f);
    }
    __syncthreads();
    if(wave == 0){
      short8 Aa[2][4];
      ld_zn_frags(zbuf + 4*4096, m16, q, Aa);
      f32x4 M[4][4];
      chain_step_A(Aa, zbuf, lane, M, false);
      float s; int e = norm_es(M, s);
      scatter_C_rm(zbuf, lane, M, s);
      if(lane == 0) Earr[b - 2] = e;
    }
    __syncthreads();
    {
      int row = tid >> 3, c0 = (tid & 7)*8;
      short8 v = lds_frag(zbuf, row, c0);
      *(short8*)(N2 + (size_t)(b - 2)*4096 + row*64 + c0) = v;
    }
  }
}

// ---------- k3: 64 N2-nodes -> M; lambda/sums on side waves; contraction; logp ----------
// zones: 0-7 chain | 8 rho_r | 9 rho_l | 10 M   (U^T reuses zone 0)
__global__ __launch_bounds__(512) void k3(const float* __restrict__ K, const u16* __restrict__ N2,
                                          const float* __restrict__ rho_r, const float* __restrict__ rho_l,
                                          const int* __restrict__ Sarr, const int* __restrict__ Earr,
                                          float* __restrict__ outp){
  __shared__ __align__(16) u16 zbuf[11*4096];
  __shared__ float sh_mu, sh_t2;
  __shared__ int sh_S, exps[8];
  const int tid = threadIdx.x, lane = tid & 63, wave = tid >> 6;
  const int m16 = lane & 15, q = lane >> 4;
  u16* zw = zbuf + wave*4096;

  // phase 0: stage rho_r -> zone8, rho_l -> zone9 (bf16 swizzled; symmetric => Zn==Zt)
  {
    int row = tid >> 3, c0 = (tid & 7)*8;
    int pos = row*64 + (((tid & 7) ^ (row & 7)) << 3);
    float pr[8], pl[8];
#pragma unroll
    for(int j = 0; j < 8; j++){ pr[j] = rho_r[row*64 + c0 + j]; pl[j] = rho_l[row*64 + c0 + j]; }
    u32x4 ur = { pack2bf(pr[0],pr[1]), pack2bf(pr[2],pr[3]), pack2bf(pr[4],pr[5]), pack2bf(pr[6],pr[7]) };
    u32x4 ul = { pack2bf(pl[0],pl[1]), pack2bf(pl[2],pl[3]), pack2bf(pl[4],pl[5]), pack2bf(pl[6],pl[7]) };
    *(short8*)(zbuf + 8*4096 + pos) = __builtin_bit_cast(short8, ur);
    *(short8*)(zbuf + 9*4096 + pos) = __builtin_bit_cast(short8, ul);
  }

  // chain-8 per wave: X_w = N2[8w+7]...N2[8w]
  {
    load_Pt_transpose(N2 + (size_t)(8*wave)*4096, zw, lane);
    short8 Af[2][4];
    f32x4 C[4][4];
#pragma unroll
    for(int j = 1; j < 7; j++){
      ld_bf16_frags(N2 + (size_t)(8*wave + j)*4096, m16, q, Af);
      chain_step_A(Af, zw, lane, C, true);
    }
    ld_bf16_frags(N2 + (size_t)(8*wave + 7)*4096, m16, q, Af);
    chain_step_A(Af, zw, lane, C, false);
    float s; int e = norm_es(C, s);
    if(!(wave & 1)) write_CT_lds_s(zw, lane, C, s);
    else            scatter_C_rm(zw, lane, C, s);
    if(lane == 0) exps[wave] = e;
  }
  __syncthreads();

  // combine L1 (waves 0-3) + side work (waves 4-6)
  if(wave < 4){
    short8 Aa[2][4];
    ld_zn_frags(zbuf + (2*wave + 1)*4096, m16, q, Aa);
    f32x4 Y[4][4];
    bool e2 = !(wave & 1);
    chain_step_A(Aa, zbuf + 2*wave*4096, lane, Y, e2);
    if(!e2) scatter_C_rm(zbuf + 2*wave*4096, lane, Y, 1.f);
  } else if(wave == 4){
    // lambda = tr(rho_l * G), G = sum_a K_a K_a^T  (A-frag == B-frag!)
    f32x4 G[4][4];
#pragma unroll
    for(int i = 0; i < 4; i++)
#pragma unroll
      for(int j = 0; j < 4; j++) G[i][j] = f32x4{0.f,0.f,0.f,0.f};
#pragma unroll 1
    for(int a = 0; a < 8; a++){
      short8 Ka[2][4];
      ld_cvt_frags(K + (size_t)a*4096, m16, q, Ka);
#pragma unroll
      for(int ks = 0; ks < 2; ks++)
#pragma unroll
        for(int i = 0; i < 4; i++)
#pragma unroll
          for(int j = 0; j < 4; j++)
            G[i][j] = mfma_bf16(Ka[ks][i], Ka[ks][j], G[i][j]);
    }
    float lp = 0.f;
#pragma unroll
    for(int i = 0; i < 4; i++)
#pragma unroll
      for(int j = 0; j < 4; j++)
#pragma unroll
        for(int t = 0; t < 4; t++){
          int r = i*16 + q*4 + t, c = j*16 + m16;
          lp += G[i][j][t] * bf2f(zbuf[9*4096 + swz(r, c)]);
        }
    for(int off = 32; off; off >>= 1) lp += __shfl_xor(lp, off, 64);
    if(lane == 0) sh_mu = lp;
  } else if(wave == 5){
    int s = Earr[lane];
#pragma unroll
    for(int kk = 0; kk < 16; kk++) s += Sarr[lane + 64*kk];
    for(int off = 32; off; off >>= 1) s += __shfl_xor(s, off, 64);
    if(lane == 0) sh_S = s;
  } else if(wave == 6){
    float t2 = 0.f;
    for(int j = 0; j < 64; j++){
      int idx = lane + 64*j;
      t2 += rho_r[idx] * rho_l[idx];
    }
    for(int off = 32; off; off >>= 1) t2 += __shfl_xor(t2, off, 64);
    if(lane == 0) sh_t2 = t2;
  }
  __syncthreads();

  // combine L2 (waves 0,1)
  if(wave < 2){
    short8 Aa[2][4];
    ld_zn_frags(zbuf + (4*wave + 2)*4096, m16, q, Aa);
    f32x4 Y[4][4];
    chain_step_A(Aa, zbuf + 4*wave*4096, lane, Y, wave == 0);
    if(wave == 1) scatter_C_rm(zbuf + 4*4096, lane, Y, 1.f);
  }
  __syncthreads();

  // L3 + contraction + final math (wave 0)
  if(wave == 0){
    short8 Aa[2][4];
    ld_zn_frags(zbuf + 4*4096, m16, q, Aa);
    f32x4 C[4][4];
    chain_step_A(Aa, zbuf, lane, C, false);
    float s; int eM = norm_es(C, s);
    u16* Pm = zbuf + 10*4096;
    scatter_C_rm(Pm, lane, C, s);          // M row-major (Zn) in zone10

    // U = M * rho_r -> U^T in zone0
    short8 Ua[2][4], Ub[2][4];
    ld_zn_frags(Pm, m16, q, Ua);
#pragma unroll
    for(int ks = 0; ks < 2; ks++)
#pragma unroll
      for(int t = 0; t < 4; t++) Ub[ks][t] = lds_frag(zbuf + 8*4096, t*16 + m16, ks*32 + q*8);
#pragma unroll
    for(int i = 0; i < 4; i++)
#pragma unroll
      for(int j = 0; j < 4; j++) C[i][j] = f32x4{0.f,0.f,0.f,0.f};
#pragma unroll
    for(int ks = 0; ks < 2; ks++)
#pragma unroll
      for(int i = 0; i < 4; i++)
#pragma unroll
        for(int j = 0; j < 4; j++)
          C[i][j] = mfma_bf16(Ua[ks][i], Ub[ks][j], C[i][j]);
    write_CT_lds(zbuf, lane, C);

    // D2 = rho_l * U
    ld_zn_frags(zbuf + 9*4096, m16, q, Ua);
#pragma unroll
    for(int ks = 0; ks < 2; ks++)
#pragma unroll
      for(int t = 0; t < 4; t++) Ub[ks][t] = lds_frag(zbuf, t*16 + m16, ks*32 + q*8);
#pragma unroll
    for(int i = 0; i < 4; i++)
#pragma unroll
      for(int j = 0; j < 4; j++) C[i][j] = f32x4{0.f,0.f,0.f,0.f};
#pragma unroll
    for(int ks = 0; ks < 2; ks++)
#pragma unroll
      for(int i = 0; i < 4; i++)
#pragma unroll
        for(int j = 0; j < 4; j++)
          C[i][j] = mfma_bf16(Ua[ks][i], Ub[ks][j], C[i][j]);

    // t1 = sum_ij D2_ij * M_ij
    float part = 0.f;
#pragma unroll
    for(int i = 0; i < 4; i++)
#pragma unroll
      for(int j = 0; j < 4; j++)
#pragma unroll
        for(int t = 0; t < 4; t++){
          int r = i*16 + q*4 + t, c = j*16 + m16;
          part += C[i][j][t] * bf2f(Pm[swz(r, c)]);
        }
    for(int off = 32; off; off >>= 1) part += __shfl_xor(part, off, 64);
    if(lane == 0){
      double t1 = (double)part;
      double S  = (double)sh_S + eM;
#pragma unroll
      for(int w = 0; w < 8; w++) S += exps[w];
      double lam = (double)sh_mu;
      double logp = 16384.0*log2(lam) - 2.0*S - log2(t1) + log2((double)sh_t2);
      outp[0] = (float)logp;
    }
  }
}

// ---------- launch ----------
extern "C" void kernel_launch(void* const* d_in, const int* in_sizes, int n_in,
                              void* d_out, int out_size, void* d_ws, size_t ws_size,
                              hipStream_t stream) {
  const float* K  = (const float*)d_in[0];   // (8,64,64) fp32
  const int* seq  = (const int*)d_in[1];     // (16384,) int32
  char* ws = (char*)d_ws;
  u16*   N1    = (u16*)(ws);                   // 1024 * 8KB = 8 MB
  u16*   N2    = (u16*)(ws + 8388608);         // 64 * 8KB = 512 KB
  float* rho_r = (float*)(ws + 8912896);       // 16 KB
  float* rho_l = (float*)(ws + 8929280);       // 16 KB
  int*   Sarr  = (int*)(ws + 8945664);         // 1024 ints
  int*   Earr  = (int*)(ws + 8949760);         // 64 ints

  k1<<<1024, 256, 0, stream>>>(K, seq, N1, Sarr);
  k2<<<66,   512, 0, stream>>>(K, N1, N2, Earr, rho_r, rho_l);
  k3<<<1,    512, 0, stream>>>(K, N2, rho_r, rho_l, Sarr, Earr, (float*)d_out);
}